// Round 5
// baseline (37014.594 us; speedup 1.0000x reference)
//
#include <hip/hip_runtime.h>
#include <math.h>

#define B_N 4096
#define E_N 512
#define C_N 8
#define NU 64
#define BK 16
#define NDEPTH 8
#define MROWS 1536   // NU*BK + E_N
#define THR 0.001f
#define EPSV 1e-8f

// ---------------- build W^T : wt[f][m], f in [0,512), m in [0,1536) ----------
// rows m<1024: W[m][f] = sum_e basis[n][e][k] * H[e][f]  (n=m>>4, k=m&15)
// rows m>=1024: W[m][f] = H[m-1024][f]
__global__ void build_wt(const float* __restrict__ basis,
                         const float* __restrict__ hasher,
                         float* __restrict__ wt) {
  const int m = blockIdx.x;
  const int t = threadIdx.x;
  float a0, a1;
  if (m < NU * BK) {
    const int n = m >> 4, k = m & 15;
    const float* bp = basis + (size_t)n * E_N * BK + k;
    a0 = 0.f; a1 = 0.f;
    for (int e = 0; e < E_N; ++e) {
      const float bv = bp[(size_t)e * BK];
      const float* hrow = hasher + (size_t)e * E_N;
      a0 = fmaf(bv, hrow[t], a0);
      a1 = fmaf(bv, hrow[t + 256], a1);
    }
  } else {
    const int e = m - NU * BK;
    a0 = hasher[(size_t)e * E_N + t];
    a1 = hasher[(size_t)e * E_N + t + 256];
  }
  wt[(size_t)t * MROWS + m] = a0;
  wt[(size_t)(t + 256) * MROWS + m] = a1;
}

// ---------------- score GEMM common geometry --------------------------------
#define SB 8      // samples per WG
#define NT 64     // cols per WG (= SB * C_N)
#define MT 256    // rows per M-tile
#define KT 16     // K per stage
#define NKS 32    // 512/16
#define NCB 512   // col-blocks = B_N/SB

// Shared inner loop: stages Ws (MT rows of wt^T slice) and Rs, accumulates
// acc[16][4] per thread; thread (tu,tc) owns rows tu*16..+15, cols tc*4..+3.
#define SCORE_KLOOP(MBASE)                                                     \
  for (int ks = 0; ks < NKS; ++ks) {                                           \
    const int kb = ks * KT;                                                    \
    const float* wrow = wt + (size_t)(kb + sk) * MROWS + (MBASE) + sch * 4;    \
    const float4 w0 = *(const float4*)(wrow);                                  \
    const float4 w1 = *(const float4*)(wrow + 64);                             \
    const float4 w2 = *(const float4*)(wrow + 128);                            \
    const float4 w3 = *(const float4*)(wrow + 192);                            \
    const float4 rv = *(const float4*)(r + ((size_t)(bb + ss) * E_N + (kb + sk)) * C_N + sh * 4); \
    __syncthreads();                                                           \
    *(float4*)&Ws[sk][sch * 4]       = w0;                                     \
    *(float4*)&Ws[sk][sch * 4 + 64]  = w1;                                     \
    *(float4*)&Ws[sk][sch * 4 + 128] = w2;                                     \
    *(float4*)&Ws[sk][sch * 4 + 192] = w3;                                     \
    *(float4*)&Rs[sk][ss * 8 + sh * 4] = rv;                                   \
    __syncthreads();                                                           \
    _Pragma("unroll")                                                          \
    for (int k = 0; k < KT; ++k) {                                             \
      float av[16];                                                            \
      *(float4*)&av[0]  = *(const float4*)&Ws[k][tu * 16];                     \
      *(float4*)&av[4]  = *(const float4*)&Ws[k][tu * 16 + 4];                 \
      *(float4*)&av[8]  = *(const float4*)&Ws[k][tu * 16 + 8];                 \
      *(float4*)&av[12] = *(const float4*)&Ws[k][tu * 16 + 12];                \
      float bv[4];                                                             \
      *(float4*)&bv[0] = *(const float4*)&Rs[k][tc * 4];                       \
      _Pragma("unroll")                                                        \
      for (int i = 0; i < 16; ++i)                                             \
        _Pragma("unroll")                                                      \
        for (int j = 0; j < 4; ++j)                                            \
          acc[i][j] = fmaf(av[i], bv[j], acc[i][j]);                           \
    }                                                                          \
  }

// ---------------- norm kernel: rows 1024..1535 -> nupart[2][B*C] ------------
__launch_bounds__(256, 6)
__global__ void norm_kernel(const float* __restrict__ r,
                            const float* __restrict__ wt,
                            float* __restrict__ nupart) {
  __shared__ __align__(16) float Ws[KT][MT];   // 16 KB
  __shared__ __align__(16) float Rs[KT][NT];   // 4 KB
  __shared__ __align__(16) float Np[16][NT];   // 4 KB
  const int tid = threadIdx.x;
  const int mt = blockIdx.x / NCB;   // 0..1 ; same-cb WGs stride NCB apart
  const int cb = blockIdx.x % NCB;   //        (NCB%8==0 -> same XCD)
  const int tu = tid >> 4, tc = tid & 15;
  const int bb = cb * SB;
  const int sk = tid >> 4, sch = tid & 15;
  const int ss = sch >> 1, sh = sch & 1;
  const int mbase = NU * BK + mt * MT;

  float acc[16][4];
#pragma unroll
  for (int i = 0; i < 16; ++i)
#pragma unroll
    for (int j = 0; j < 4; ++j) acc[i][j] = 0.f;

  SCORE_KLOOP(mbase)

#pragma unroll
  for (int j = 0; j < 4; ++j) {
    float s = 0.f;
#pragma unroll
    for (int i = 0; i < 16; ++i) s = fmaf(acc[i][j], acc[i][j], s);
    Np[tu][tc * 4 + j] = s;
  }
  __syncthreads();
  if (tid < NT) {
    float nu = 0.f;
    for (int t16 = 0; t16 < 16; ++t16) nu += Np[t16][tid];  // deterministic
    nupart[(size_t)mt * B_N * C_N + (size_t)bb * C_N + tid] = nu;
  }
}

// ---------------- unit score kernel: rows 0..1023 -> sfin[B][NU] ------------
__launch_bounds__(256, 6)
__global__ void unit_score_kernel(const float* __restrict__ r,
                                  const float* __restrict__ wt,
                                  const float* __restrict__ nupart,
                                  float* __restrict__ sfin) {
  __shared__ __align__(16) float Ws[KT][MT];   // 16 KB
  __shared__ __align__(16) float Rs[KT][NT];   // 4 KB
  __shared__ __align__(16) float Sc[16][NT];   // 4 KB
  __shared__ __align__(16) float scale_s[NT];
  const int tid = threadIdx.x;
  const int mt = blockIdx.x / NCB;   // 0..3
  const int cb = blockIdx.x % NCB;
  const int tu = tid >> 4, tc = tid & 15;
  const int bb = cb * SB;
  const int sk = tid >> 4, sch = tid & 15;
  const int ss = sch >> 1, sh = sch & 1;
  const int mbase = mt * MT;

  float acc[16][4];
#pragma unroll
  for (int i = 0; i < 16; ++i)
#pragma unroll
    for (int j = 0; j < 4; ++j) acc[i][j] = 0.f;

  SCORE_KLOOP(mbase)

  // per-thread z^2 reduction over this unit's 16 rows (thread-local, exact order)
#pragma unroll
  for (int j = 0; j < 4; ++j) {
    float s = 0.f;
#pragma unroll
    for (int i = 0; i < 16; ++i) s = fmaf(acc[i][j], acc[i][j], s);
    Sc[tu][tc * 4 + j] = s;
  }
  if (tid < NT) {
    const size_t g = (size_t)bb * C_N + tid;
    const float nu = nupart[g] + nupart[(size_t)B_N * C_N + g];
    const float inv = 1.f / (sqrtf(nu) + EPSV);
    scale_s[tid] = inv * inv;
  }
  __syncthreads();
  if (tid < 128) {
    const int ul = tid >> 3, bs = tid & 7;   // unit-local, sample-local
    float s = 0.f;
#pragma unroll
    for (int c = 0; c < C_N; ++c)
      s = fmaf(Sc[ul][bs * 8 + c], scale_s[bs * 8 + c], s);
    sfin[(size_t)(bb + bs) * NU + mt * 16 + ul] = s;
  }
}

// ---------------- update kernel: one WG per sample (argmax fused) -----------
#define BSP 17   // padded stride for basis tile (kills 16-way bank conflict)

__launch_bounds__(256)
__global__ void update_kernel(const float* __restrict__ basis,
                              float* __restrict__ r,
                              const float* __restrict__ sfin,
                              unsigned char* __restrict__ used,
                              float* __restrict__ init_energy,
                              const int depth) {
  __shared__ __align__(16) float rs[E_N * C_N];     // 16 KB
  __shared__ __align__(16) float bsh[E_N * BSP];    // ~34.8 KB
  __shared__ __align__(16) float coeffs[BK * C_N];  // coeffs[k*8+c]
  __shared__ __align__(16) float part[2][BK * C_N];
  __shared__ __align__(16) float epart[256];
  __shared__ float sval[NU];
  __shared__ int sbu;
  const int b = blockIdx.x;
  const int tid = threadIdx.x;
  float* rb = r + (size_t)b * E_N * C_N;

  // fused argmax (scores >= 0; used -> -1 sentinel; first-max-wins like argmax)
  if (tid < NU) {
    float s = sfin[(size_t)b * NU + tid];
    if (used[(size_t)b * NU + tid]) s = -1.f;
    sval[tid] = s;
  }

  float en = 0.f;
  for (int i = tid; i < E_N * C_N / 4; i += 256) {   // 4 iters
    const float4 v = ((const float4*)rb)[i];
    *(float4*)&rs[i * 4] = v;
    en = fmaf(v.x, v.x, en); en = fmaf(v.y, v.y, en);
    en = fmaf(v.z, v.z, en); en = fmaf(v.w, v.w, en);
  }
  epart[tid] = en;
  __syncthreads();
  if (tid == 0) {
    float bs = -2.f; int bi = 0;
    for (int u = 0; u < NU; ++u)
      if (sval[u] > bs) { bs = sval[u]; bi = u; }
    sbu = bi;
  }
  for (int s = 128; s > 0; s >>= 1) {   // deterministic tree reduce
    if (tid < s) epart[tid] += epart[tid + s];
    __syncthreads();
  }
  const float etot = epart[0];
  const int bu = sbu;                   // valid: barrier above after sbu write
  const float* bp = basis + (size_t)bu * E_N * BK;

  for (int i = tid; i < E_N * BK / 4; i += 256) {    // 8 iters
    const float4 v = ((const float4*)bp)[i];
    const int f0 = i * 4;
    const int e = f0 >> 4, k = f0 & 15;
    bsh[e * BSP + k]     = v.x;
    bsh[e * BSP + k + 1] = v.y;
    bsh[e * BSP + k + 2] = v.z;
    bsh[e * BSP + k + 3] = v.w;
  }
  __syncthreads();

  {  // coeffs[k,c] = sum_e bsel[e,k] * r[e,c], two halves then ordered combine
    const int p = tid & 127;
    const int k = p >> 3, c = p & 7;
    const int h = tid >> 7;
    const int e0 = h * 256;
    float s = 0.f;
    for (int e = e0; e < e0 + 256; ++e)
      s = fmaf(bsh[e * BSP + k], rs[e * 8 + c], s);
    part[h][p] = s;
  }
  __syncthreads();
  if (tid < 128) coeffs[tid] = part[0][tid] + part[1][tid];
  __syncthreads();

  float ie;
  if (depth == 0) {
    ie = etot;
    if (tid == 0) init_energy[b] = etot;
  } else {
    ie = init_energy[b];
  }
  const bool act = etot > THR * ie;
  if (act) {
#pragma unroll
    for (int q = 0; q < 4; ++q) {
      const int i4 = q * 256 + tid;         // float4 index in [0,1024)
      const int e = i4 >> 1, c0 = (i4 & 1) * 4;
      float p0 = 0.f, p1 = 0.f, p2 = 0.f, p3 = 0.f;
#pragma unroll
      for (int k = 0; k < BK; ++k) {
        const float bv = bsh[e * BSP + k];
        p0 = fmaf(bv, coeffs[k * 8 + c0], p0);
        p1 = fmaf(bv, coeffs[k * 8 + c0 + 1], p1);
        p2 = fmaf(bv, coeffs[k * 8 + c0 + 2], p2);
        p3 = fmaf(bv, coeffs[k * 8 + c0 + 3], p3);
      }
      float4 v = ((const float4*)rs)[i4];
      v.x -= p0; v.y -= p1; v.z -= p2; v.w -= p3;
      ((float4*)rb)[i4] = v;
    }
    if (tid == 0) used[(size_t)b * NU + bu] = 1;
  }
}

// ---------------- finalize: out = x - r_final -------------------------------
__global__ void finalize_kernel(const float* __restrict__ x,
                                const float* __restrict__ r,
                                float* __restrict__ out) {
  const int i = blockIdx.x * blockDim.x + threadIdx.x;
  const float4 xv = ((const float4*)x)[i];
  const float4 rv = ((const float4*)r)[i];
  float4 o;
  o.x = xv.x - rv.x; o.y = xv.y - rv.y;
  o.z = xv.z - rv.z; o.w = xv.w - rv.w;
  ((float4*)out)[i] = o;
}

extern "C" void kernel_launch(void* const* d_in, const int* in_sizes, int n_in,
                              void* d_out, int out_size, void* d_ws, size_t ws_size,
                              hipStream_t stream) {
  const float* x      = (const float*)d_in[0];
  const float* basis  = (const float*)d_in[1];
  const float* hasher = (const float*)d_in[2];
  float* out = (float*)d_out;

  // workspace layout (~68.5 MB)
  float* r           = (float*)d_ws;                        // 16,777,216 f
  float* wt          = r + (size_t)B_N * E_N * C_N;         //    786,432 f
  float* nupart      = wt + (size_t)E_N * MROWS;            //     65,536 f
  float* sfin        = nupart + (size_t)2 * B_N * C_N;      //    262,144 f
  float* init_energy = sfin + (size_t)B_N * NU;             //      4,096 f
  unsigned char* used = (unsigned char*)(init_energy + B_N);//    262,144 B

  hipMemcpyAsync(r, x, (size_t)B_N * E_N * C_N * sizeof(float),
                 hipMemcpyDeviceToDevice, stream);
  hipMemsetAsync(used, 0, (size_t)B_N * NU, stream);
  build_wt<<<MROWS, 256, 0, stream>>>(basis, hasher, wt);

  for (int d = 0; d < NDEPTH; ++d) {
    norm_kernel<<<2 * NCB, 256, 0, stream>>>(r, wt, nupart);
    unit_score_kernel<<<4 * NCB, 256, 0, stream>>>(r, wt, nupart, sfin);
    update_kernel<<<B_N, 256, 0, stream>>>(basis, r, sfin, used, init_energy, d);
  }
  finalize_kernel<<<(B_N * E_N * C_N / 4) / 256, 256, 0, stream>>>(x, r, out);
}

// Round 6
// 5183.619 us; speedup vs baseline: 7.1407x; 7.1407x over previous
//
#include <hip/hip_runtime.h>
#include <math.h>

#define B_N 4096
#define E_N 512
#define C_N 8
#define NU 64
#define BK 16
#define NDEPTH 8
#define MROWS 1536   // NU*BK + E_N
#define THR 0.001f
#define EPSV 1e-8f

// ---------------- build W^T : wt[f][m], f in [0,512), m in [0,1536) ----------
// rows m<1024: W[m][f] = sum_e basis[n][e][k] * H[e][f]  (n=m>>4, k=m&15)
// rows m>=1024: W[m][f] = H[m-1024][f]
__global__ void build_wt(const float* __restrict__ basis,
                         const float* __restrict__ hasher,
                         float* __restrict__ wt) {
  const int m = blockIdx.x;
  const int t = threadIdx.x;
  float a0, a1;
  if (m < NU * BK) {
    const int n = m >> 4, k = m & 15;
    const float* bp = basis + (size_t)n * E_N * BK + k;
    a0 = 0.f; a1 = 0.f;
    for (int e = 0; e < E_N; ++e) {
      const float bv = bp[(size_t)e * BK];
      const float* hrow = hasher + (size_t)e * E_N;
      a0 = fmaf(bv, hrow[t], a0);
      a1 = fmaf(bv, hrow[t + 256], a1);
    }
  } else {
    const int e = m - NU * BK;
    a0 = hasher[(size_t)e * E_N + t];
    a1 = hasher[(size_t)e * E_N + t + 256];
  }
  wt[(size_t)t * MROWS + m] = a0;
  wt[(size_t)(t + 256) * MROWS + m] = a1;
}

// ---------------- score GEMM common geometry --------------------------------
#define SB 8      // samples per WG
#define NT 64     // cols per WG (= SB * C_N)
#define MT 256    // rows per M-tile
#define KT 16     // K per stage
#define NKS 32    // 512/16
#define NCB 512   // col-blocks = B_N/SB

// Shared inner loop: stages Ws (MT rows of wt^T slice) and Rs, accumulates
// acc[16][4] per thread; thread (tu,tc) owns rows tu*16..+15, cols tc*4..+3.
#define SCORE_KLOOP(MBASE)                                                     \
  for (int ks = 0; ks < NKS; ++ks) {                                           \
    const int kb = ks * KT;                                                    \
    const float* wrow = wt + (size_t)(kb + sk) * MROWS + (MBASE) + sch * 4;    \
    const float4 w0 = *(const float4*)(wrow);                                  \
    const float4 w1 = *(const float4*)(wrow + 64);                             \
    const float4 w2 = *(const float4*)(wrow + 128);                            \
    const float4 w3 = *(const float4*)(wrow + 192);                            \
    const float4 rv = *(const float4*)(r + ((size_t)(bb + ss) * E_N + (kb + sk)) * C_N + sh * 4); \
    __syncthreads();                                                           \
    *(float4*)&Ws[sk][sch * 4]       = w0;                                     \
    *(float4*)&Ws[sk][sch * 4 + 64]  = w1;                                     \
    *(float4*)&Ws[sk][sch * 4 + 128] = w2;                                     \
    *(float4*)&Ws[sk][sch * 4 + 192] = w3;                                     \
    *(float4*)&Rs[sk][ss * 8 + sh * 4] = rv;                                   \
    __syncthreads();                                                           \
    _Pragma("unroll")                                                          \
    for (int k = 0; k < KT; ++k) {                                             \
      float av[16];                                                            \
      *(float4*)&av[0]  = *(const float4*)&Ws[k][tu * 16];                     \
      *(float4*)&av[4]  = *(const float4*)&Ws[k][tu * 16 + 4];                 \
      *(float4*)&av[8]  = *(const float4*)&Ws[k][tu * 16 + 8];                 \
      *(float4*)&av[12] = *(const float4*)&Ws[k][tu * 16 + 12];                \
      float bv[4];                                                             \
      *(float4*)&bv[0] = *(const float4*)&Rs[k][tc * 4];                       \
      _Pragma("unroll")                                                        \
      for (int i = 0; i < 16; ++i)                                             \
        _Pragma("unroll")                                                      \
        for (int j = 0; j < 4; ++j)                                            \
          acc[i][j] = fmaf(av[i], bv[j], acc[i][j]);                           \
    }                                                                          \
  }

// NOTE: launch_bounds min-waves arg must stay <= 4. At (256,6) the per-SIMD
// 512-reg pool with 64-reg granularity caps VGPR at 64 -> acc[16][4] spills
// to scratch (round 5: VGPR 40, WRITE_SIZE 10 GB/dispatch, 6.7x regression).
// At (256,4): cap 128, compiler uses ~68 -> 4 blocks/CU, no spill.

// ---------------- norm kernel: rows 1024..1535 -> nupart[2][B*C] ------------
__launch_bounds__(256, 4)
__global__ void norm_kernel(const float* __restrict__ r,
                            const float* __restrict__ wt,
                            float* __restrict__ nupart) {
  __shared__ __align__(16) float Ws[KT][MT];   // 16 KB
  __shared__ __align__(16) float Rs[KT][NT];   // 4 KB
  __shared__ __align__(16) float Np[16][NT];   // 4 KB
  const int tid = threadIdx.x;
  const int mt = blockIdx.x / NCB;   // 0..1 ; same-cb WGs stride NCB apart
  const int cb = blockIdx.x % NCB;   //        (NCB%8==0 -> same XCD)
  const int tu = tid >> 4, tc = tid & 15;
  const int bb = cb * SB;
  const int sk = tid >> 4, sch = tid & 15;
  const int ss = sch >> 1, sh = sch & 1;
  const int mbase = NU * BK + mt * MT;

  float acc[16][4];
#pragma unroll
  for (int i = 0; i < 16; ++i)
#pragma unroll
    for (int j = 0; j < 4; ++j) acc[i][j] = 0.f;

  SCORE_KLOOP(mbase)

#pragma unroll
  for (int j = 0; j < 4; ++j) {
    float s = 0.f;
#pragma unroll
    for (int i = 0; i < 16; ++i) s = fmaf(acc[i][j], acc[i][j], s);
    Np[tu][tc * 4 + j] = s;
  }
  __syncthreads();
  if (tid < NT) {
    float nu = 0.f;
    for (int t16 = 0; t16 < 16; ++t16) nu += Np[t16][tid];  // deterministic
    nupart[(size_t)mt * B_N * C_N + (size_t)bb * C_N + tid] = nu;
  }
}

// ---------------- unit score kernel: rows 0..1023 -> sfin[B][NU] ------------
__launch_bounds__(256, 4)
__global__ void unit_score_kernel(const float* __restrict__ r,
                                  const float* __restrict__ wt,
                                  const float* __restrict__ nupart,
                                  float* __restrict__ sfin) {
  __shared__ __align__(16) float Ws[KT][MT];   // 16 KB
  __shared__ __align__(16) float Rs[KT][NT];   // 4 KB
  __shared__ __align__(16) float Sc[16][NT];   // 4 KB
  __shared__ __align__(16) float scale_s[NT];
  const int tid = threadIdx.x;
  const int mt = blockIdx.x / NCB;   // 0..3
  const int cb = blockIdx.x % NCB;
  const int tu = tid >> 4, tc = tid & 15;
  const int bb = cb * SB;
  const int sk = tid >> 4, sch = tid & 15;
  const int ss = sch >> 1, sh = sch & 1;
  const int mbase = mt * MT;

  float acc[16][4];
#pragma unroll
  for (int i = 0; i < 16; ++i)
#pragma unroll
    for (int j = 0; j < 4; ++j) acc[i][j] = 0.f;

  SCORE_KLOOP(mbase)

  // per-thread z^2 reduction over this unit's 16 rows (thread-local, exact order)
#pragma unroll
  for (int j = 0; j < 4; ++j) {
    float s = 0.f;
#pragma unroll
    for (int i = 0; i < 16; ++i) s = fmaf(acc[i][j], acc[i][j], s);
    Sc[tu][tc * 4 + j] = s;
  }
  if (tid < NT) {
    const size_t g = (size_t)bb * C_N + tid;
    const float nu = nupart[g] + nupart[(size_t)B_N * C_N + g];
    const float inv = 1.f / (sqrtf(nu) + EPSV);
    scale_s[tid] = inv * inv;
  }
  __syncthreads();
  if (tid < 128) {
    const int ul = tid >> 3, bs = tid & 7;   // unit-local, sample-local
    float s = 0.f;
#pragma unroll
    for (int c = 0; c < C_N; ++c)
      s = fmaf(Sc[ul][bs * 8 + c], scale_s[bs * 8 + c], s);
    sfin[(size_t)(bb + bs) * NU + mt * 16 + ul] = s;
  }
}

// ---------------- update kernel: one WG per sample (argmax fused) -----------
#define BSP 17   // padded stride for basis tile (kills 16-way bank conflict)

__launch_bounds__(256)
__global__ void update_kernel(const float* __restrict__ basis,
                              float* __restrict__ r,
                              const float* __restrict__ sfin,
                              unsigned char* __restrict__ used,
                              float* __restrict__ init_energy,
                              const int depth) {
  __shared__ __align__(16) float rs[E_N * C_N];     // 16 KB
  __shared__ __align__(16) float bsh[E_N * BSP];    // ~34.8 KB
  __shared__ __align__(16) float coeffs[BK * C_N];  // coeffs[k*8+c]
  __shared__ __align__(16) float part[2][BK * C_N];
  __shared__ __align__(16) float epart[256];
  __shared__ float sval[NU];
  __shared__ int sbu;
  const int b = blockIdx.x;
  const int tid = threadIdx.x;
  float* rb = r + (size_t)b * E_N * C_N;

  // fused argmax (scores >= 0; used -> -1 sentinel; first-max-wins like argmax)
  if (tid < NU) {
    float s = sfin[(size_t)b * NU + tid];
    if (used[(size_t)b * NU + tid]) s = -1.f;
    sval[tid] = s;
  }

  float en = 0.f;
  for (int i = tid; i < E_N * C_N / 4; i += 256) {   // 4 iters
    const float4 v = ((const float4*)rb)[i];
    *(float4*)&rs[i * 4] = v;
    en = fmaf(v.x, v.x, en); en = fmaf(v.y, v.y, en);
    en = fmaf(v.z, v.z, en); en = fmaf(v.w, v.w, en);
  }
  epart[tid] = en;
  __syncthreads();
  if (tid == 0) {
    float bs = -2.f; int bi = 0;
    for (int u = 0; u < NU; ++u)
      if (sval[u] > bs) { bs = sval[u]; bi = u; }
    sbu = bi;
  }
  for (int s = 128; s > 0; s >>= 1) {   // deterministic tree reduce
    if (tid < s) epart[tid] += epart[tid + s];
    __syncthreads();
  }
  const float etot = epart[0];
  const int bu = sbu;                   // valid: barrier above after sbu write
  const float* bp = basis + (size_t)bu * E_N * BK;

  for (int i = tid; i < E_N * BK / 4; i += 256) {    // 8 iters
    const float4 v = ((const float4*)bp)[i];
    const int f0 = i * 4;
    const int e = f0 >> 4, k = f0 & 15;
    bsh[e * BSP + k]     = v.x;
    bsh[e * BSP + k + 1] = v.y;
    bsh[e * BSP + k + 2] = v.z;
    bsh[e * BSP + k + 3] = v.w;
  }
  __syncthreads();

  {  // coeffs[k,c] = sum_e bsel[e,k] * r[e,c], two halves then ordered combine
    const int p = tid & 127;
    const int k = p >> 3, c = p & 7;
    const int h = tid >> 7;
    const int e0 = h * 256;
    float s = 0.f;
    for (int e = e0; e < e0 + 256; ++e)
      s = fmaf(bsh[e * BSP + k], rs[e * 8 + c], s);
    part[h][p] = s;
  }
  __syncthreads();
  if (tid < 128) coeffs[tid] = part[0][tid] + part[1][tid];
  __syncthreads();

  float ie;
  if (depth == 0) {
    ie = etot;
    if (tid == 0) init_energy[b] = etot;
  } else {
    ie = init_energy[b];
  }
  const bool act = etot > THR * ie;
  if (act) {
#pragma unroll
    for (int q = 0; q < 4; ++q) {
      const int i4 = q * 256 + tid;         // float4 index in [0,1024)
      const int e = i4 >> 1, c0 = (i4 & 1) * 4;
      float p0 = 0.f, p1 = 0.f, p2 = 0.f, p3 = 0.f;
#pragma unroll
      for (int k = 0; k < BK; ++k) {
        const float bv = bsh[e * BSP + k];
        p0 = fmaf(bv, coeffs[k * 8 + c0], p0);
        p1 = fmaf(bv, coeffs[k * 8 + c0 + 1], p1);
        p2 = fmaf(bv, coeffs[k * 8 + c0 + 2], p2);
        p3 = fmaf(bv, coeffs[k * 8 + c0 + 3], p3);
      }
      float4 v = ((const float4*)rs)[i4];
      v.x -= p0; v.y -= p1; v.z -= p2; v.w -= p3;
      ((float4*)rb)[i4] = v;
    }
    if (tid == 0) used[(size_t)b * NU + bu] = 1;
  }
}

// ---------------- finalize: out = x - r_final -------------------------------
__global__ void finalize_kernel(const float* __restrict__ x,
                                const float* __restrict__ r,
                                float* __restrict__ out) {
  const int i = blockIdx.x * blockDim.x + threadIdx.x;
  const float4 xv = ((const float4*)x)[i];
  const float4 rv = ((const float4*)r)[i];
  float4 o;
  o.x = xv.x - rv.x; o.y = xv.y - rv.y;
  o.z = xv.z - rv.z; o.w = xv.w - rv.w;
  ((float4*)out)[i] = o;
}

extern "C" void kernel_launch(void* const* d_in, const int* in_sizes, int n_in,
                              void* d_out, int out_size, void* d_ws, size_t ws_size,
                              hipStream_t stream) {
  const float* x      = (const float*)d_in[0];
  const float* basis  = (const float*)d_in[1];
  const float* hasher = (const float*)d_in[2];
  float* out = (float*)d_out;

  // workspace layout (~68.5 MB)
  float* r           = (float*)d_ws;                        // 16,777,216 f
  float* wt          = r + (size_t)B_N * E_N * C_N;         //    786,432 f
  float* nupart      = wt + (size_t)E_N * MROWS;            //     65,536 f
  float* sfin        = nupart + (size_t)2 * B_N * C_N;      //    262,144 f
  float* init_energy = sfin + (size_t)B_N * NU;             //      4,096 f
  unsigned char* used = (unsigned char*)(init_energy + B_N);//    262,144 B

  hipMemcpyAsync(r, x, (size_t)B_N * E_N * C_N * sizeof(float),
                 hipMemcpyDeviceToDevice, stream);
  hipMemsetAsync(used, 0, (size_t)B_N * NU, stream);
  build_wt<<<MROWS, 256, 0, stream>>>(basis, hasher, wt);

  for (int d = 0; d < NDEPTH; ++d) {
    norm_kernel<<<2 * NCB, 256, 0, stream>>>(r, wt, nupart);
    unit_score_kernel<<<4 * NCB, 256, 0, stream>>>(r, wt, nupart, sfin);
    update_kernel<<<B_N, 256, 0, stream>>>(basis, r, sfin, used, init_energy, d);
  }
  finalize_kernel<<<(B_N * E_N * C_N / 4) / 256, 256, 0, stream>>>(x, r, out);
}

// Round 7
// 2253.466 us; speedup vs baseline: 16.4256x; 2.3003x over previous
//
#include <hip/hip_runtime.h>
#include <math.h>

#define B_N 4096
#define E_N 512
#define C_N 8
#define NU 64
#define BK 16
#define NDEPTH 8
#define MROWS 1536   // NU*BK + E_N
#define THR 0.001f
#define EPSV 1e-8f
#define NTOT (B_N * C_N)   // 32768 score columns
#define NQ 4               // quarters (bounds workspace)
#define NQC (NTOT / NQ)    // 8192 cols per quarter
#define NQB (B_N / NQ)     // 1024 samples per quarter
#define WSCALE 64.0f       // lifts W entries (~0.04) out of fp16-subnormal range

typedef _Float16 f16;
typedef f16 f16x8 __attribute__((ext_vector_type(8)));
typedef float f32x4 __attribute__((ext_vector_type(4)));

// ---------------- build W (fp16 hi/lo, scaled): W[m][e], m in [0,1536) ------
// m<1024: W[m][e] = WSCALE * sum_f basis[n][f][k] * H[f][e]  (n=m>>4, k=m&15)
// m>=1024: W[m][e] = WSCALE * H[m-1024][e]
__global__ void build_w(const float* __restrict__ basis,
                        const float* __restrict__ hasher,
                        f16* __restrict__ whi, f16* __restrict__ wlo) {
  const int m = blockIdx.x;
  const int t = threadIdx.x;
  float a0, a1;
  if (m < NU * BK) {
    const int n = m >> 4, k = m & 15;
    const float* bp = basis + (size_t)n * E_N * BK + k;
    a0 = 0.f; a1 = 0.f;
    for (int e = 0; e < E_N; ++e) {
      const float bv = bp[(size_t)e * BK];
      const float* hrow = hasher + (size_t)e * E_N;
      a0 = fmaf(bv, hrow[t], a0);
      a1 = fmaf(bv, hrow[t + 256], a1);
    }
  } else {
    const int e = m - NU * BK;
    a0 = hasher[(size_t)e * E_N + t];
    a1 = hasher[(size_t)e * E_N + t + 256];
  }
  a0 *= WSCALE; a1 *= WSCALE;
  const f16 h0 = (f16)a0, h1 = (f16)a1;
  whi[(size_t)m * E_N + t] = h0;
  wlo[(size_t)m * E_N + t] = (f16)(a0 - (float)h0);
  whi[(size_t)m * E_N + t + 256] = h1;
  wlo[(size_t)m * E_N + t + 256] = (f16)(a1 - (float)h1);
}

// ---------------- transpose+convert: r[b][e][c] -> rT[(b-bq0)*8+c][e] -------
// Per-sample power-of-2 scaling (max -> [32,64)) keeps fp16 lo terms normal;
// the scale cancels exactly in score = part/(sqrt(nu)+eps)^2 (argmax-invariant).
#define TP (E_N + 4)   // padded LDS stride (bank spread)
__launch_bounds__(256)
__global__ void transpose_conv(const float* __restrict__ r,
                               f16* __restrict__ rThi, f16* __restrict__ rTlo,
                               const int bq0) {
  __shared__ float T[C_N * TP];    // [c][e]
  __shared__ float red[256];
  const int tid = threadIdx.x;
  const int b = bq0 + blockIdx.x;
  const float* rb = r + (size_t)b * E_N * C_N;
  float mx = 0.f;
  for (int i = tid; i < E_N * C_N / 4; i += 256) {
    const float4 v = ((const float4*)rb)[i];
    const int e = i >> 1, c4 = (i & 1) * 4;
    T[(c4 + 0) * TP + e] = v.x;
    T[(c4 + 1) * TP + e] = v.y;
    T[(c4 + 2) * TP + e] = v.z;
    T[(c4 + 3) * TP + e] = v.w;
    mx = fmaxf(mx, fmaxf(fmaxf(fabsf(v.x), fabsf(v.y)),
                         fmaxf(fabsf(v.z), fabsf(v.w))));
  }
  red[tid] = mx;
  __syncthreads();
  for (int s = 128; s > 0; s >>= 1) {
    if (tid < s) red[tid] = fmaxf(red[tid], red[tid + s]);
    __syncthreads();
  }
  const float m0 = red[0];
  int ex; frexpf(m0, &ex);                       // m0 = f*2^ex, f in [0.5,1)
  const float sc = (m0 > 0.f) ? ldexpf(1.f, 6 - ex) : 1.f;  // max -> [32,64)
  const int c = tid >> 5, o = tid & 31;          // 8 c-rows x 32 e-chunks
  const size_t row = (size_t)(blockIdx.x * C_N + c) * E_N;  // quarter-local
  const float* Trow = &T[c * TP + o * 16];
  f16x8 hv0, hv1, lv0, lv1;
#pragma unroll
  for (int j = 0; j < 8; ++j) {
    const float v = Trow[j] * sc;
    const f16 h = (f16)v;
    hv0[j] = h; lv0[j] = (f16)(v - (float)h);
  }
#pragma unroll
  for (int j = 0; j < 8; ++j) {
    const float v = Trow[8 + j] * sc;
    const f16 h = (f16)v;
    hv1[j] = h; lv1[j] = (f16)(v - (float)h);
  }
  *(f16x8*)&rThi[row + o * 16]     = hv0;
  *(f16x8*)&rThi[row + o * 16 + 8] = hv1;
  *(f16x8*)&rTlo[row + o * 16]     = lv0;
  *(f16x8*)&rTlo[row + o * 16 + 8] = lv1;
}

// ---------------- MFMA score kernel -----------------------------------------
// z = W*rT^T via 3-term fp16 split: Whi*rhi + Whi*rlo + Wlo*rhi (fp32 acc).
// 128x128 tile, 4 waves (2Mx2N), BK=32, 16 K-steps. Epilogue reduces z^2:
// unit tiles (m0<1024) -> part[u][n]; norm tiles -> nupart[tile][n].
__launch_bounds__(256, 2)
__global__ void mfma_score(const f16* __restrict__ whi, const f16* __restrict__ wlo,
                           const f16* __restrict__ rThi, const f16* __restrict__ rTlo,
                           float* __restrict__ part, float* __restrict__ nupart,
                           const int n0) {
  __shared__ f16 Ah[128 * 32], Al[128 * 32], Bh[128 * 32], Bl[128 * 32];
  __shared__ float nred[2][128];
  const int tid = threadIdx.x;
  const int lane = tid & 63;
  const int w = tid >> 6, wm = w >> 1, wn = w & 1;
  // XCD-aware swizzle: 768 blocks = 8 XCDs x 96; each XCD gets 8 full
  // B-panels x 12 M-tiles -> B-panel L2-resident per XCD.
  const int bid = blockIdx.x;
  const int nid = (bid & 7) * 96 + (bid >> 3);
  const int mt = nid % 12, nt = nid / 12;
  const int m0 = mt * 128;
  const int nq0 = nt * 128;
  const int l15 = lane & 15, lk = lane >> 4;

  const f32x4 fz = {0.f, 0.f, 0.f, 0.f};
  f32x4 acc[4][4];
#pragma unroll
  for (int i = 0; i < 4; ++i)
#pragma unroll
    for (int j = 0; j < 4; ++j) acc[i][j] = fz;

  // staging map: h = it*256+tid; row = h>>2; chunk = h&3 (8 halves = 16B)
  const int h0 = tid, h1 = 256 + tid;
  const int r0 = h0 >> 2, c0 = h0 & 3, r1 = h1 >> 2, c1 = h1 & 3;
  const int s0 = (h0 & ~3) | (c0 ^ (r0 & 3));   // XOR chunk swizzle
  const int s1 = (h1 & ~3) | (c1 ^ (r1 & 3));
  const size_t aoff0 = (size_t)(m0 + r0) * E_N + c0 * 8;
  const size_t aoff1 = (size_t)(m0 + r1) * E_N + c1 * 8;
  const size_t boff0 = (size_t)(nq0 + r0) * E_N + c0 * 8;
  const size_t boff1 = (size_t)(nq0 + r1) * E_N + c1 * 8;

  f16x8 vah0 = *(const f16x8*)(whi + aoff0);
  f16x8 vah1 = *(const f16x8*)(whi + aoff1);
  f16x8 val0 = *(const f16x8*)(wlo + aoff0);
  f16x8 val1 = *(const f16x8*)(wlo + aoff1);
  f16x8 vbh0 = *(const f16x8*)(rThi + boff0);
  f16x8 vbh1 = *(const f16x8*)(rThi + boff1);
  f16x8 vbl0 = *(const f16x8*)(rTlo + boff0);
  f16x8 vbl1 = *(const f16x8*)(rTlo + boff1);

  for (int ks = 0; ks < 16; ++ks) {
    __syncthreads();
    ((f16x8*)Ah)[s0] = vah0; ((f16x8*)Ah)[s1] = vah1;
    ((f16x8*)Al)[s0] = val0; ((f16x8*)Al)[s1] = val1;
    ((f16x8*)Bh)[s0] = vbh0; ((f16x8*)Bh)[s1] = vbh1;
    ((f16x8*)Bl)[s0] = vbl0; ((f16x8*)Bl)[s1] = vbl1;
    __syncthreads();
    if (ks < 15) {   // prefetch next K-step (overlaps MFMA below)
      const size_t ko = (size_t)(ks + 1) * 32;
      vah0 = *(const f16x8*)(whi + aoff0 + ko);
      vah1 = *(const f16x8*)(whi + aoff1 + ko);
      val0 = *(const f16x8*)(wlo + aoff0 + ko);
      val1 = *(const f16x8*)(wlo + aoff1 + ko);
      vbh0 = *(const f16x8*)(rThi + boff0 + ko);
      vbh1 = *(const f16x8*)(rThi + boff1 + ko);
      vbl0 = *(const f16x8*)(rTlo + boff0 + ko);
      vbl1 = *(const f16x8*)(rTlo + boff1 + ko);
    }
    f16x8 bhf[4], blf[4];
#pragma unroll
    for (int fn = 0; fn < 4; ++fn) {
      const int row = wn * 64 + fn * 16 + l15;
      const int idx = row * 4 + (lk ^ (row & 3));
      bhf[fn] = ((const f16x8*)Bh)[idx];
      blf[fn] = ((const f16x8*)Bl)[idx];
    }
#pragma unroll
    for (int fm = 0; fm < 4; ++fm) {
      const int row = wm * 64 + fm * 16 + l15;
      const int idx = row * 4 + (lk ^ (row & 3));
      const f16x8 ahf = ((const f16x8*)Ah)[idx];
      const f16x8 alf = ((const f16x8*)Al)[idx];
#pragma unroll
      for (int fn = 0; fn < 4; ++fn) {
        acc[fm][fn] = __builtin_amdgcn_mfma_f32_16x16x32_f16(ahf, bhf[fn], acc[fm][fn], 0, 0, 0);
        acc[fm][fn] = __builtin_amdgcn_mfma_f32_16x16x32_f16(ahf, blf[fn], acc[fm][fn], 0, 0, 0);
        acc[fm][fn] = __builtin_amdgcn_mfma_f32_16x16x32_f16(alf, bhf[fn], acc[fm][fn], 0, 0, 0);
      }
    }
  }

  // epilogue: C/D frag layout col = lane&15, row = (lane>>4)*4 + reg
  if (m0 < NU * BK) {
#pragma unroll
    for (int fm = 0; fm < 4; ++fm) {
      const int u = (m0 >> 4) + wm * 4 + fm;
#pragma unroll
      for (int fn = 0; fn < 4; ++fn) {
        const f32x4 a = acc[fm][fn];
        float s = a.x * a.x + a.y * a.y + a.z * a.z + a.w * a.w;
        s += __shfl_xor(s, 16);
        s += __shfl_xor(s, 32);   // 16-row (one unit) column sum
        if (lk == 0)
          part[(size_t)u * NTOT + n0 + nq0 + wn * 64 + fn * 16 + l15] = s;
      }
    }
  } else {
#pragma unroll
    for (int fn = 0; fn < 4; ++fn) {
      float s = 0.f;
#pragma unroll
      for (int fm = 0; fm < 4; ++fm) {
        const f32x4 a = acc[fm][fn];
        s += a.x * a.x + a.y * a.y + a.z * a.z + a.w * a.w;
      }
      s += __shfl_xor(s, 16);
      s += __shfl_xor(s, 32);   // 64-row (wave) column sum
      if (lk == 0) nred[wm][wn * 64 + fn * 16 + l15] = s;
    }
    __syncthreads();
    if (tid < 128)
      nupart[(size_t)((m0 - NU * BK) >> 7) * NTOT + n0 + nq0 + tid] =
          nred[0][tid] + nred[1][tid];
  }
}

// ---------------- update kernel: scale+score+argmax fused -------------------
#define BSP 17   // padded stride for basis tile (kills 16-way bank conflict)

__launch_bounds__(256)
__global__ void update_kernel(const float* __restrict__ basis,
                              float* __restrict__ r,
                              const float* __restrict__ part,
                              const float* __restrict__ nupart,
                              unsigned char* __restrict__ used,
                              float* __restrict__ init_energy,
                              const int depth) {
  __shared__ __align__(16) float rs[E_N * C_N];     // 16 KB
  __shared__ __align__(16) float bsh[E_N * BSP];    // ~34.8 KB
  __shared__ __align__(16) float coeffs[BK * C_N];
  __shared__ __align__(16) float prt[2][BK * C_N];
  __shared__ __align__(16) float epart[256];
  __shared__ float sval[NU];
  __shared__ float scale_sh[C_N];
  __shared__ int sbu;
  const int b = blockIdx.x;
  const int tid = threadIdx.x;
  float* rb = r + (size_t)b * E_N * C_N;

  if (tid < C_N) {   // per-c scale from norm partials (W/r scaling cancels)
    float nu = 0.f;
#pragma unroll
    for (int t4 = 0; t4 < 4; ++t4)
      nu += nupart[(size_t)t4 * NTOT + b * C_N + tid];
    const float inv = 1.f / (sqrtf(nu) + EPSV);
    scale_sh[tid] = inv * inv;
  }
  float en = 0.f;
  for (int i = tid; i < E_N * C_N / 4; i += 256) {   // 4 iters
    const float4 v = ((const float4*)rb)[i];
    *(float4*)&rs[i * 4] = v;
    en = fmaf(v.x, v.x, en); en = fmaf(v.y, v.y, en);
    en = fmaf(v.z, v.z, en); en = fmaf(v.w, v.w, en);
  }
  epart[tid] = en;
  __syncthreads();
  if (tid < NU) {    // score[u] = sum_c part[u][b,c] * scale[c]; mask used
    const float* pu = part + (size_t)tid * NTOT + b * C_N;
    const float4 p0 = *(const float4*)pu;
    const float4 p1 = *(const float4*)(pu + 4);
    float s = p0.x * scale_sh[0];
    s = fmaf(p0.y, scale_sh[1], s);
    s = fmaf(p0.z, scale_sh[2], s);
    s = fmaf(p0.w, scale_sh[3], s);
    s = fmaf(p1.x, scale_sh[4], s);
    s = fmaf(p1.y, scale_sh[5], s);
    s = fmaf(p1.z, scale_sh[6], s);
    s = fmaf(p1.w, scale_sh[7], s);
    if (used[(size_t)b * NU + tid]) s = -1.f;   // scores >= 0
    sval[tid] = s;
  }
  for (int s = 128; s > 0; s >>= 1) {   // deterministic tree reduce (energy)
    if (tid < s) epart[tid] += epart[tid + s];
    __syncthreads();
  }
  if (tid == 0) {   // first-max-wins argmax (matches jnp.argmax)
    float bs = -2.f; int bi = 0;
    for (int u = 0; u < NU; ++u)
      if (sval[u] > bs) { bs = sval[u]; bi = u; }
    sbu = bi;
  }
  __syncthreads();
  const float etot = epart[0];
  const int bu = sbu;
  const float* bp = basis + (size_t)bu * E_N * BK;

  for (int i = tid; i < E_N * BK / 4; i += 256) {    // 8 iters
    const float4 v = ((const float4*)bp)[i];
    const int f0 = i * 4;
    const int e = f0 >> 4, k = f0 & 15;
    bsh[e * BSP + k]     = v.x;
    bsh[e * BSP + k + 1] = v.y;
    bsh[e * BSP + k + 2] = v.z;
    bsh[e * BSP + k + 3] = v.w;
  }
  __syncthreads();

  {  // coeffs[k,c] = sum_e bsel[e,k] * r[e,c], two halves, ordered combine
    const int p = tid & 127;
    const int k = p >> 3, c = p & 7;
    const int h = tid >> 7;
    const int e0 = h * 256;
    float s = 0.f;
    for (int e = e0; e < e0 + 256; ++e)
      s = fmaf(bsh[e * BSP + k], rs[e * 8 + c], s);
    prt[h][p] = s;
  }
  __syncthreads();
  if (tid < 128) coeffs[tid] = prt[0][tid] + prt[1][tid];
  __syncthreads();

  float ie;
  if (depth == 0) {
    ie = etot;
    if (tid == 0) init_energy[b] = etot;
  } else {
    ie = init_energy[b];
  }
  const bool act = etot > THR * ie;
  if (act) {
#pragma unroll
    for (int q = 0; q < 4; ++q) {
      const int i4 = q * 256 + tid;
      const int e = i4 >> 1, c0 = (i4 & 1) * 4;
      float p0 = 0.f, p1 = 0.f, p2 = 0.f, p3 = 0.f;
#pragma unroll
      for (int k = 0; k < BK; ++k) {
        const float bv = bsh[e * BSP + k];
        p0 = fmaf(bv, coeffs[k * 8 + c0], p0);
        p1 = fmaf(bv, coeffs[k * 8 + c0 + 1], p1);
        p2 = fmaf(bv, coeffs[k * 8 + c0 + 2], p2);
        p3 = fmaf(bv, coeffs[k * 8 + c0 + 3], p3);
      }
      float4 v = ((const float4*)rs)[i4];
      v.x -= p0; v.y -= p1; v.z -= p2; v.w -= p3;
      ((float4*)rb)[i4] = v;
    }
    if (tid == 0) used[(size_t)b * NU + bu] = 1;
  }
}

// ---------------- finalize: out = x - r_final -------------------------------
__global__ void finalize_kernel(const float* __restrict__ x,
                                const float* __restrict__ r,
                                float* __restrict__ out) {
  const int i = blockIdx.x * blockDim.x + threadIdx.x;
  const float4 xv = ((const float4*)x)[i];
  const float4 rv = ((const float4*)r)[i];
  float4 o;
  o.x = xv.x - rv.x; o.y = xv.y - rv.y;
  o.z = xv.z - rv.z; o.w = xv.w - rv.w;
  ((float4*)out)[i] = o;
}

extern "C" void kernel_launch(void* const* d_in, const int* in_sizes, int n_in,
                              void* d_out, int out_size, void* d_ws, size_t ws_size,
                              hipStream_t stream) {
  const float* x      = (const float*)d_in[0];
  const float* basis  = (const float*)d_in[1];
  const float* hasher = (const float*)d_in[2];
  float* out = (float*)d_out;

  // workspace layout (~96.2 MB)
  float* r    = (float*)d_ws;                               // 16,777,216 f
  f16*   whi  = (f16*)(r + (size_t)B_N * E_N * C_N);        //   786,432 h
  f16*   wlo  = whi + (size_t)MROWS * E_N;                  //   786,432 h
  f16*   rThi = wlo + (size_t)MROWS * E_N;                  // 4,194,304 h
  f16*   rTlo = rThi + (size_t)NQC * E_N;                   // 4,194,304 h
  float* part = (float*)(rTlo + (size_t)NQC * E_N);         // 2,097,152 f
  float* nupart = part + (size_t)NU * NTOT;                 //   131,072 f
  float* init_energy = nupart + (size_t)4 * NTOT;           //     4,096 f
  unsigned char* used = (unsigned char*)(init_energy + B_N);//   262,144 B

  hipMemcpyAsync(r, x, (size_t)B_N * E_N * C_N * sizeof(float),
                 hipMemcpyDeviceToDevice, stream);
  hipMemsetAsync(used, 0, (size_t)B_N * NU, stream);
  build_w<<<MROWS, 256, 0, stream>>>(basis, hasher, whi, wlo);

  for (int d = 0; d < NDEPTH; ++d) {
    for (int q = 0; q < NQ; ++q) {
      transpose_conv<<<NQB, 256, 0, stream>>>(r, rThi, rTlo, q * NQB);
      mfma_score<<<768, 256, 0, stream>>>(whi, wlo, rThi, rTlo,
                                          part, nupart, q * NQC);
    }
    update_kernel<<<B_N, 256, 0, stream>>>(basis, r, part, nupart, used,
                                           init_energy, d);
  }
  finalize_kernel<<<(B_N * E_N * C_N / 4) / 256, 256, 0, stream>>>(x, r, out);
}